// Round 7
// baseline (306.828 us; speedup 1.0000x reference)
//
#include <hip/hip_runtime.h>

// DHSMoEDetector: N=16384 tokens, D=768, H=768, C=2, E=20
#define N_D 768
#define N_H 768
#define N_C 2
#define N_E 20
#define MG 64            // token rows per block (m-group)
#define KT 24            // K-steps of 32 (768/32)
#define SLOTMAX 96
#define ROWB (N_D * 2)   // bf16 row stride in bytes

typedef __attribute__((ext_vector_type(8))) short short8;
typedef __attribute__((ext_vector_type(4))) float f32x4;

__device__ __forceinline__ unsigned short f2bf(float f) {
  unsigned u = __builtin_bit_cast(unsigned, f);
  u += 0x7FFFu + ((u >> 16) & 1u);
  return (unsigned short)(u >> 16);
}

#define GLD_LDS16(gp, lp)                                                        \
  __builtin_amdgcn_global_load_lds(                                              \
      (const __attribute__((address_space(1))) void*)(gp),                       \
      (__attribute__((address_space(3))) void*)(lp), 16, 0, 0)

// ---------------- k_prep: zero out + hist + scan + slots + scatter ----------
// One 1024-thread block; replaces 2 memsets + 3 kernels (launch-gap savings).

__global__ __launch_bounds__(1024) void k_prep(const int* __restrict__ cidx,
                                               int n, int* __restrict__ counts,
                                               int* __restrict__ offsets,
                                               int* __restrict__ slots,
                                               int* __restrict__ sorted,
                                               float* __restrict__ out,
                                               int out_elems) {
  __shared__ int lcnt[N_E], lbase[N_E], lcur[N_E];
  const int tid = threadIdx.x;
  for (int i = tid; i < out_elems; i += 1024) out[i] = 0.f;
  if (tid < N_E) lcnt[tid] = 0;
  __syncthreads();
  const int rounds = (n + 1023) >> 10;
  for (int r = 0; r < rounds; ++r) {
    int i = tid + (r << 10);
    if (i < n) {
      int e = cidx[i];
      e = e < 0 ? 0 : (e >= N_E ? N_E - 1 : e);
      atomicAdd(&lcnt[e], 1);
    }
  }
  __syncthreads();
  if (tid == 0) {
    int run = 0;
    for (int e = 0; e < N_E; ++e) {
      lbase[e] = run;
      run += lcnt[e];
    }
  }
  __syncthreads();
  if (tid < N_E) {
    counts[tid] = lcnt[tid];
    offsets[tid] = lbase[tid];
    lcur[tid] = lbase[tid];
  }
  if (tid >= 64 && tid < 72) {  // 8 slot builders, one per XCD
    int x = tid - 64, idx = 0;
    for (int e = x; e < N_E; e += 8) {
      int nt = (lcnt[e] + MG - 1) / MG;
      for (int m = 0; m < nt && idx < SLOTMAX; ++m)
        slots[x * SLOTMAX + idx++] = e | (m << 8);
    }
    for (; idx < SLOTMAX; ++idx) slots[x * SLOTMAX + idx] = -1;
  }
  __syncthreads();
  for (int r = 0; r < rounds; ++r) {
    int i = tid + (r << 10);
    if (i < n) {
      int e = cidx[i];
      e = e < 0 ? 0 : (e >= N_E ? N_E - 1 : e);
      int p = atomicAdd(&lcur[e], 1);
      sorted[p] = i;
    }
  }
}

// ---------------- k_cvt: gather (sorted, fp32->bf16) + W1 transpose --------

__global__ __launch_bounds__(256) void k_cvt(const float* __restrict__ emb,
                                             const int* __restrict__ sorted,
                                             unsigned short* __restrict__ Xg,
                                             int n, int pcap,
                                             const float* __restrict__ W1,
                                             unsigned short* __restrict__ W1t) {
  __shared__ float tile[64][65];
  int b = blockIdx.x;
  if (b < pcap) {
    int j = threadIdx.x;
    if (j < 192) {
      ushort4 o;
      if (b < n) {
        float4 v = ((const float4*)(emb + (size_t)sorted[b] * N_D))[j];
        o.x = f2bf(v.x);
        o.y = f2bf(v.y);
        o.z = f2bf(v.z);
        o.w = f2bf(v.w);
      } else {
        o.x = o.y = o.z = o.w = 0;
      }
      ((ushort4*)(Xg + (size_t)b * N_D))[j] = o;
    }
    return;
  }
  b -= pcap;
  int e = b / 144, rem = b % 144;
  int h0 = (rem % 12) * 64, d0 = (rem / 12) * 64;
  const float* src = W1 + (size_t)e * N_D * N_H;
  unsigned short* dst = W1t + (size_t)e * N_H * N_D;
  int tx = threadIdx.x & 15, ty = threadIdx.x >> 4;
  for (int s = 0; s < 4; ++s) {
    int d = s * 16 + ty;
    float4 v = *(const float4*)&src[(size_t)(d0 + d) * N_H + h0 + tx * 4];
    tile[d][tx * 4 + 0] = v.x;
    tile[d][tx * 4 + 1] = v.y;
    tile[d][tx * 4 + 2] = v.z;
    tile[d][tx * 4 + 3] = v.w;
  }
  __syncthreads();
  int px = threadIdx.x & 7, py = threadIdx.x >> 3;
  for (int s = 0; s < 2; ++s) {
    int h = s * 32 + py;
    short8 v;
    for (int j = 0; j < 8; ++j)
      v[j] = (short)f2bf(tile[px * 8 + j][h]);
    *(short8*)&dst[(size_t)(h0 + h) * N_D + d0 + px * 8] = v;
  }
}

// ---------------- k_gemm: barrierless-K fused MoE layer ---------------------
// Block = 512 thr (8 waves), one (expert, 64-token group). A-slab 64x768 bf16
// staged to LDS ONCE (96 KB, chunk-major per 16-row group) -> zero barriers in
// the K-loop. Each wave owns 32 rows x 192 cols; B-fragments stream from
// global (W1t is K-contiguous) directly into VGPRs, interleaved 1:1 with MFMA
// (AITER-style per-wave vmcnt pipelining, no block coupling). Epilogue fuses
// relu + layer2 (h . W2) with lane-16 shfl reduce + atomics into out.

__global__ __launch_bounds__(512, 2) void k_gemm(
    const unsigned short* __restrict__ Xg, const unsigned short* __restrict__ W1t,
    const float* __restrict__ b1, const float* __restrict__ W2,
    const float* __restrict__ b2, const int* __restrict__ sorted,
    const int* __restrict__ counts, const int* __restrict__ offsets,
    const int* __restrict__ slots, float* __restrict__ out) {
  const int sv = slots[(blockIdx.x & 7) * SLOTMAX + (blockIdx.x >> 3)];
  if (sv < 0) return;
  const int e = sv & 255;
  const int m0 = (sv >> 8) * MG;
  const int off = offsets[e];
  const int cnt_rel = counts[e] - m0;

  __shared__ unsigned short lA[KT * 16 * 128];  // 96 KB: [kt][grp*4+quad][lm*8]

  const int tid = threadIdx.x;
  const int wid = tid >> 6, lane = tid & 63;
  const int rg = wid >> 2;  // row 32-group (0..1)
  const int cs = wid & 3;   // col slab of 192 (0..3)
  const int quad = lane >> 4, lm = lane & 15;

  // ---- stage A slab: 96 x global_load_lds_dwordx4 (12 per wave), 1 barrier
  const char* abase = (const char*)Xg + (size_t)(off + m0) * ROWB;
  for (int t = 0; t < 12; ++t) {
    int idx = wid * 12 + t;  // 0..95 -> kt = idx>>2, grp = idx&3
    int kt = idx >> 2, grp = idx & 3;
    const char* gp = abase + (size_t)(grp * 16 + lm) * ROWB + kt * 64 + quad * 16;
    GLD_LDS16(gp, (char*)lA + ((size_t)idx << 10));
  }

  // ---- B fragment pointers: frag(ct,kt) = 16B at bbase + ct*16*ROWB + kt*64
  const char* bbase = (const char*)W1t +
                      ((size_t)e * N_H + cs * 192 + lm) * ROWB + quad * 16;
  float4 bq[12];
#pragma unroll
  for (int ct = 0; ct < 12; ++ct)
    bq[ct] = *(const float4*)(bbase + ct * 16 * ROWB);  // kt = 0

  __syncthreads();  // drains staging; lA read-only from here on

  f32x4 acc[2][12] = {};

#pragma unroll
  for (int kt = 0; kt < KT; ++kt) {
    // A frags (LDS, conflict-free): row-tile i -> grp = rg*2+i
    short8 a0 = *(const short8*)&lA[(kt * 16 + (rg * 2 + 0) * 4 + quad) * 128 + lm * 8];
    short8 a1 = *(const short8*)&lA[(kt * 16 + (rg * 2 + 1) * 4 + quad) * 128 + lm * 8];
#pragma unroll
    for (int ct = 0; ct < 12; ++ct) {
      short8 b = __builtin_bit_cast(short8, bq[ct]);
      acc[0][ct] = __builtin_amdgcn_mfma_f32_16x16x32_bf16(a0, b, acc[0][ct], 0, 0, 0);
      acc[1][ct] = __builtin_amdgcn_mfma_f32_16x16x32_bf16(a1, b, acc[1][ct], 0, 0, 0);
      if (kt < KT - 1)
        bq[ct] = *(const float4*)(bbase + ct * 16 * ROWB + (kt + 1) * 64);
    }
  }

  // ---- fused epilogue: h = relu(acc + b1), y = h . W2[e]; C/D layout:
  // col = lm, row (within 16-tile) = quad*4 + r
  float y0[2][4], y1[2][4];
  for (int i = 0; i < 2; ++i)
    for (int r = 0; r < 4; ++r) y0[i][r] = y1[i][r] = 0.f;

#pragma unroll
  for (int ct = 0; ct < 12; ++ct) {
    int col = cs * 192 + ct * 16 + lm;
    float bias = b1[e * N_H + col];
    float2 w2 = *(const float2*)&W2[((size_t)e * N_H + col) * N_C];
    for (int i = 0; i < 2; ++i) {
      f32x4 a = acc[i][ct];
      for (int r = 0; r < 4; ++r) {
        float h = a[r] + bias;
        h = h > 0.f ? h : 0.f;
        y0[i][r] += h * w2.x;
        y1[i][r] += h * w2.y;
      }
    }
  }
  for (int s = 1; s < 16; s <<= 1) {
    for (int i = 0; i < 2; ++i)
      for (int r = 0; r < 4; ++r) {
        y0[i][r] += __shfl_xor(y0[i][r], s, 64);
        y1[i][r] += __shfl_xor(y1[i][r], s, 64);
      }
  }
  if (lm == 0) {
    float bb0 = (cs == 0) ? b2[e * N_C + 0] : 0.f;
    float bb1 = (cs == 0) ? b2[e * N_C + 1] : 0.f;
    for (int i = 0; i < 2; ++i) {
      for (int r = 0; r < 4; ++r) {
        int mrel = rg * 32 + i * 16 + quad * 4 + r;
        if (mrel < cnt_rel) {
          int token = sorted[off + m0 + mrel];
          atomicAdd(&out[(size_t)token * N_C + 0], y0[i][r] + bb0);
          atomicAdd(&out[(size_t)token * N_C + 1], y1[i][r] + bb1);
        }
      }
    }
  }
}

// ---------------- launch: THREE dispatches ----------------------------------

extern "C" void kernel_launch(void* const* d_in, const int* in_sizes, int n_in,
                              void* d_out, int out_size, void* d_ws, size_t ws_size,
                              hipStream_t stream) {
  const float* emb = (const float*)d_in[0];
  const int* cidx = (const int*)d_in[1];
  const float* W1 = (const float*)d_in[2];
  const float* b1 = (const float*)d_in[3];
  const float* W2 = (const float*)d_in[4];
  const float* b2 = (const float*)d_in[5];
  float* out = (float*)d_out;
  const int n = in_sizes[1];

  // ws: 0 counts[32] | 128 offsets[32] | 1024 slots[8*96] | 8192 sorted[n]
  //     | Xg bf16 (n+MG)*768 | W1t bf16 E*768*768
  char* ws = (char*)d_ws;
  int* counts = (int*)ws;
  int* offsets = (int*)(ws + 128);
  int* slots = (int*)(ws + 1024);
  int* sorted = (int*)(ws + 8192);
  size_t sorted_bytes = ((size_t)n * 4 + 255) & ~(size_t)255;
  unsigned short* Xg = (unsigned short*)(ws + 8192 + sorted_bytes);
  int pcap = n + MG;  // zero-padded tail rows
  unsigned short* W1t = Xg + (size_t)pcap * N_D;

  k_prep<<<1, 1024, 0, stream>>>(cidx, n, counts, offsets, slots, sorted, out,
                                 out_size);
  k_cvt<<<pcap + N_E * 144, 256, 0, stream>>>(emb, sorted, Xg, n, pcap, W1, W1t);
  k_gemm<<<8 * SLOTMAX, 512, 0, stream>>>(Xg, W1t, b1, W2, b2, sorted, counts,
                                          offsets, slots, out);
}